// Round 4
// baseline (108.309 us; speedup 1.0000x reference)
//
#include <hip/hip_runtime.h>

#define HH 512
#define WW 512
#define NB 8
#define NC 128
#define TW 64
#define TH 64
#define NTILES 64            // 8x8 tiles of 64x64
#define NBLK (NB * NTILES)   // 512
#define CUT 30.0f            // exp(-30) ~ 9e-14 << 2e-2 tolerance
#define POISON_I ((int)0xAAAAAAAA)

// ws: [0, NBLK) float2 partials {scale_sum, hm_sum}; [NBLK*8] int done-counter.
// Counter starts at harness poison 0xAAAAAAAA (re-poisoned before every
// launch). Each block release-stores its partial then fetch_add(1) on the
// counter; the block seeing old == POISON_I + NBLK - 1 is last: it
// acquire-loads all partials ONCE (no spinning — round 3 showed polling
// regresses 20 µs) and writes out[0..1].

__global__ __launch_bounds__(256) void ahl_main_kernel(
    const float* __restrict__ pred_hm,
    const float* __restrict__ pred_sm,
    const float* __restrict__ mask,
    const float* __restrict__ ground_res,
    const int*   __restrict__ centers,
    float* __restrict__ out,            // out[0]=sl, out[1]=hl, gts at out+2
    float2* __restrict__ pp,            // NBLK partials
    int* __restrict__ done_cnt) {
    __shared__ float4 sp[NC];
    __shared__ float4 sc[NC];
    __shared__ int s_cnt;
    __shared__ float red[8];
    __shared__ int s_last;

    const int b    = blockIdx.x >> 6;
    const int tile = blockIdx.x & 63;
    const int tx0  = (tile & 7) * TW;
    const int ty0  = (tile >> 3) * TH;
    const int tid  = threadIdx.x;

    // ---- phase 0: per-center params (gathers are L2-hot across blocks)
    if (tid == 0) s_cnt = 0;
    if (tid < NC) {
        int cy = centers[(b * NC + tid) * 2 + 0];
        int cx = centers[(b * NC + tid) * 2 + 1];
        cy = min(max(cy, 0), HH - 1);
        cx = min(max(cx, 0), WW - 1);
        float sm = pred_sm[(size_t)b * HH * WW + (size_t)cy * WW + cx];
        float g  = ground_res[b];
        float size = (0.2f / g) * (1.0f + fmaxf(sm, 0.0f));
        float s = 0.70710678f / size;          // sqrt(1/(2 size^2))
        sp[tid] = make_float4(s, -(float)cx * s, -(float)cy * s, 0.0f);
    }
    __syncthreads();

    // ---- phase 1: cull centers vs tile rect (scaled distance)
    if (tid < NC) {
        float4 P = sp[tid];
        float a0 = fmaf((float)tx0,            P.x, P.y);
        float a1 = fmaf((float)(tx0 + TW - 1), P.x, P.y);
        float b0 = fmaf((float)ty0,            P.x, P.z);
        float b1 = fmaf((float)(ty0 + TH - 1), P.x, P.z);
        float dx = fmaxf(0.0f, fmaxf(a0, -a1));
        float dy = fmaxf(0.0f, fmaxf(b0, -b1));
        if (fmaf(dx, dx, dy * dy) < CUT) {
            int i = atomicAdd(&s_cnt, 1);
            sc[i] = P;
        }
    }
    __syncthreads();
    const int cnt = s_cnt;

    // ---- phase 2: min-splat. thread = 4 consecutive cols x 4 strided rows
    const int cg = tid & 15;
    const int rt = tid >> 4;
    const int x0 = tx0 + cg * 4;
    float xf[4], yf[4];
#pragma unroll
    for (int j = 0; j < 4; j++) xf[j] = (float)(x0 + j);
#pragma unroll
    for (int r = 0; r < 4; r++) yf[r] = (float)(ty0 + rt + r * 16);

    float m[4][4];
#pragma unroll
    for (int r = 0; r < 4; r++)
#pragma unroll
        for (int j = 0; j < 4; j++) m[r][j] = 1e30f;

    for (int i = 0; i < cnt; i++) {
        float4 P = sc[i];
        float dx2[4];
#pragma unroll
        for (int j = 0; j < 4; j++) {
            float d = fmaf(xf[j], P.x, P.y);
            dx2[j] = d * d;
        }
#pragma unroll
        for (int r = 0; r < 4; r++) {
            float dys = fmaf(yf[r], P.x, P.z);
            float a = dys * dys;
#pragma unroll
            for (int j = 0; j < 4; j++)
                m[r][j] = fminf(m[r][j], dx2[j] + a);
        }
    }

    // ---- phase 3: epilogue — float4 loads, float2 gt stores (out+2 offset)
    float lhm = 0.0f, lsc = 0.0f;
    const size_t sbase = (size_t)b * HH * WW;
#pragma unroll
    for (int r = 0; r < 4; r++) {
        size_t idx = sbase + (size_t)(ty0 + rt + r * 16) * WW + x0;
        float4 hm4 = *(const float4*)&pred_hm[idx];
        float4 sm4 = *(const float4*)&pred_sm[idx];
        float4 mk4 = *(const float4*)&mask[idx];
        float g0 = __expf(-m[r][0]);
        float g1 = __expf(-m[r][1]);
        float g2 = __expf(-m[r][2]);
        float g3 = __expf(-m[r][3]);
        float2* gp = (float2*)&out[2 + idx];   // 8B-aligned (idx % 4 == 0)
        gp[0] = make_float2(g0, g1);
        gp[1] = make_float2(g2, g3);
        float d0 = hm4.x - g0, d1 = hm4.y - g1, d2 = hm4.z - g2, d3 = hm4.w - g3;
        lhm = fmaf(d0 * d0, mk4.x, lhm);
        lhm = fmaf(d1 * d1, mk4.y, lhm);
        lhm = fmaf(d2 * d2, mk4.z, lhm);
        lhm = fmaf(d3 * d3, mk4.w, lhm);
        lsc = fmaf(sm4.x, sm4.x, lsc);
        lsc = fmaf(sm4.y, sm4.y, lsc);
        lsc = fmaf(sm4.z, sm4.z, lsc);
        lsc = fmaf(sm4.w, sm4.w, lsc);
    }

    // block reduction
#pragma unroll
    for (int off = 32; off > 0; off >>= 1) {
        lhm += __shfl_down(lhm, off);
        lsc += __shfl_down(lsc, off);
    }
    int lane = tid & 63, wid = tid >> 6;
    if (lane == 0) { red[wid] = lsc; red[4 + wid] = lhm; }
    __syncthreads();
    if (tid == 0) {
        float ts = red[0] + red[1] + red[2] + red[3];
        float th = red[4] + red[5] + red[6] + red[7];
        // publish partial (release), then bump the done counter (acq_rel)
        __hip_atomic_store(&pp[blockIdx.x].x, ts, __ATOMIC_RELAXED,
                           __HIP_MEMORY_SCOPE_AGENT);
        __hip_atomic_store(&pp[blockIdx.x].y, th, __ATOMIC_RELEASE,
                           __HIP_MEMORY_SCOPE_AGENT);
        int old = __hip_atomic_fetch_add(done_cnt, 1, __ATOMIC_ACQ_REL,
                                         __HIP_MEMORY_SCOPE_AGENT);
        s_last = (old == POISON_I + NBLK - 1) ? 1 : 0;
    }
    __syncthreads();

    // ---- last finishing block: one-shot gather of all partials, final write
    if (s_last) {
        float ts = 0.0f, th = 0.0f;
        for (int s = tid; s < NBLK; s += 256) {   // 2 slots per thread
            float a = __hip_atomic_load(&pp[s].x, __ATOMIC_RELAXED,
                                        __HIP_MEMORY_SCOPE_AGENT);
            float c = __hip_atomic_load(&pp[s].y, __ATOMIC_ACQUIRE,
                                        __HIP_MEMORY_SCOPE_AGENT);
            ts += a;
            th += c;
        }
#pragma unroll
        for (int off = 32; off > 0; off >>= 1) {
            ts += __shfl_down(ts, off);
            th += __shfl_down(th, off);
        }
        __syncthreads();   // red[] reuse
        if (lane == 0) { red[wid] = ts; red[4 + wid] = th; }
        __syncthreads();
        if (tid == 0) {
            const float invc = 1.0f / (float)((size_t)NB * HH * WW);
            out[0] = (red[0] + red[1] + red[2] + red[3]) * invc;
            out[1] = (red[4] + red[5] + red[6] + red[7]) * invc;
        }
    }
}

extern "C" void kernel_launch(void* const* d_in, const int* in_sizes, int n_in,
                              void* d_out, int out_size, void* d_ws, size_t ws_size,
                              hipStream_t stream) {
    const float* pred_hm    = (const float*)d_in[0];
    const float* pred_sm    = (const float*)d_in[1];
    const float* ground_res = (const float*)d_in[2];
    const float* mask       = (const float*)d_in[3];
    const int*   centers    = (const int*)d_in[4];
    float* out = (float*)d_out;
    float2* pp = (float2*)d_ws;                          // NBLK float2
    int* done_cnt = (int*)((char*)d_ws + NBLK * 8);      // starts at 0xAAAAAAAA

    ahl_main_kernel<<<NBLK, 256, 0, stream>>>(pred_hm, pred_sm, mask,
                                              ground_res, centers, out, pp,
                                              done_cnt);
}

// Round 5
// 85.341 us; speedup vs baseline: 1.2691x; 1.2691x over previous
//
#include <hip/hip_runtime.h>

#define HH 512
#define WW 512
#define NB 8
#define NC 128
#define TW 64                 // tile width (pixels)
#define TH 16                 // tile height (pixels)
#define NTILES 256            // (512/64) x (512/16) = 8 x 32 per sample
#define NBLK (NB * NTILES)    // 2048 blocks -> 8192 waves -> 100% occ ceiling
#define CUT 30.0f             // exp(-30) ~ 9e-14 << 2e-2 tolerance

// R4 post-mortem: 512-block grid = 2 waves/SIMD -> latency-bound (VALUBusy
// 2.4%). This version: 2048 blocks, 1 row x 4 px per thread, epilogue loads
// prefetched at kernel entry, plain-store partials + separate reduce kernel
// (fused agent-atomic reduction bought nothing; keep hot kernel clean).

__global__ __launch_bounds__(256) void ahl_main_kernel(
    const float* __restrict__ pred_hm,
    const float* __restrict__ pred_sm,
    const float* __restrict__ mask,
    const float* __restrict__ ground_res,
    const int*   __restrict__ centers,
    float* __restrict__ out,            // out[0]=sl, out[1]=hl, gts at out+2
    float2* __restrict__ partials) {
    __shared__ float4 sp[NC];
    __shared__ float4 sc[NC];
    __shared__ int s_cnt;
    __shared__ float red[8];

    const int b    = blockIdx.x >> 8;          // / NTILES
    const int tile = blockIdx.x & 255;
    const int tx0  = (tile & 7) * TW;
    const int ty0  = (tile >> 3) * TH;
    const int tid  = threadIdx.x;

    // thread -> 1 row x 4 consecutive cols
    const int cg  = tid & 15;                  // col group (x4 px)
    const int row = tid >> 4;                  // 0..15
    const int x0  = tx0 + cg * 4;
    const int y   = ty0 + row;

    // ---- prefetch epilogue data NOW; latency overlaps phases 0-2
    const size_t sbase = (size_t)b * HH * WW;
    const size_t idx   = sbase + (size_t)y * WW + x0;
    float4 hm4 = *(const float4*)&pred_hm[idx];
    float4 sm4 = *(const float4*)&pred_sm[idx];
    float4 mk4 = *(const float4*)&mask[idx];

    // ---- phase 0: per-center params (gathers L2-hot across blocks)
    if (tid == 0) s_cnt = 0;
    if (tid < NC) {
        int cy = centers[(b * NC + tid) * 2 + 0];
        int cx = centers[(b * NC + tid) * 2 + 1];
        cy = min(max(cy, 0), HH - 1);
        cx = min(max(cx, 0), WW - 1);
        float smv = pred_sm[sbase + (size_t)cy * WW + cx];
        float g   = ground_res[b];
        float size = (0.2f / g) * (1.0f + fmaxf(smv, 0.0f));
        float s = 0.70710678f / size;          // sqrt(1/(2 size^2))
        sp[tid] = make_float4(s, -(float)cx * s, -(float)cy * s, 0.0f);
    }
    __syncthreads();

    // ---- phase 1: cull centers vs tile rect (scaled distance)
    if (tid < NC) {
        float4 P = sp[tid];
        float a0 = fmaf((float)tx0,            P.x, P.y);
        float a1 = fmaf((float)(tx0 + TW - 1), P.x, P.y);
        float b0 = fmaf((float)ty0,            P.x, P.z);
        float b1 = fmaf((float)(ty0 + TH - 1), P.x, P.z);
        float dx = fmaxf(0.0f, fmaxf(a0, -a1));
        float dy = fmaxf(0.0f, fmaxf(b0, -b1));
        if (fmaf(dx, dx, dy * dy) < CUT) {
            int i = atomicAdd(&s_cnt, 1);
            sc[i] = P;
        }
    }
    __syncthreads();
    const int cnt = s_cnt;

    // ---- phase 2: min-splat over culled centers (m[4] only — no spill)
    const float yfv = (float)y;
    float xf[4];
#pragma unroll
    for (int j = 0; j < 4; j++) xf[j] = (float)(x0 + j);
    float m[4] = {1e30f, 1e30f, 1e30f, 1e30f};

    for (int i = 0; i < cnt; i++) {
        float4 P = sc[i];
        float dys = fmaf(yfv, P.x, P.z);
        float a = dys * dys;
#pragma unroll
        for (int j = 0; j < 4; j++) {
            float d = fmaf(xf[j], P.x, P.y);
            m[j] = fminf(m[j], fmaf(d, d, a));
        }
    }

    // ---- phase 3: epilogue (data already in registers)
    float g0 = __expf(-m[0]);
    float g1 = __expf(-m[1]);
    float g2 = __expf(-m[2]);
    float g3 = __expf(-m[3]);
    float2* gp = (float2*)&out[2 + idx];       // 8B-aligned (idx % 4 == 0)
    gp[0] = make_float2(g0, g1);
    gp[1] = make_float2(g2, g3);

    float d0 = hm4.x - g0, d1 = hm4.y - g1, d2 = hm4.z - g2, d3 = hm4.w - g3;
    float lhm = d0 * d0 * mk4.x;
    lhm = fmaf(d1 * d1, mk4.y, lhm);
    lhm = fmaf(d2 * d2, mk4.z, lhm);
    lhm = fmaf(d3 * d3, mk4.w, lhm);
    float lsc = sm4.x * sm4.x;
    lsc = fmaf(sm4.y, sm4.y, lsc);
    lsc = fmaf(sm4.z, sm4.z, lsc);
    lsc = fmaf(sm4.w, sm4.w, lsc);

    // block reduction
#pragma unroll
    for (int off = 32; off > 0; off >>= 1) {
        lhm += __shfl_down(lhm, off);
        lsc += __shfl_down(lsc, off);
    }
    int lane = tid & 63, wid = tid >> 6;
    if (lane == 0) { red[wid] = lsc; red[4 + wid] = lhm; }
    __syncthreads();
    if (tid == 0) {
        float ts = red[0] + red[1] + red[2] + red[3];
        float th = red[4] + red[5] + red[6] + red[7];
        partials[blockIdx.x] = make_float2(ts, th);   // plain store; kernel
    }                                                  // boundary orders it
}

__global__ __launch_bounds__(256) void ahl_reduce_kernel(
    const float2* __restrict__ partials, float* __restrict__ out) {
    __shared__ float red[8];
    const int tid = threadIdx.x;
    float ts = 0.0f, th = 0.0f;
    for (int s = tid; s < NBLK; s += 256) {    // 8 slots per thread
        float2 a = partials[s];
        ts += a.x;
        th += a.y;
    }
#pragma unroll
    for (int off = 32; off > 0; off >>= 1) {
        ts += __shfl_down(ts, off);
        th += __shfl_down(th, off);
    }
    int lane = tid & 63, wid = tid >> 6;
    if (lane == 0) { red[wid] = ts; red[4 + wid] = th; }
    __syncthreads();
    if (tid == 0) {
        const float invc = 1.0f / (float)((size_t)NB * HH * WW);
        out[0] = (red[0] + red[1] + red[2] + red[3]) * invc;
        out[1] = (red[4] + red[5] + red[6] + red[7]) * invc;
    }
}

extern "C" void kernel_launch(void* const* d_in, const int* in_sizes, int n_in,
                              void* d_out, int out_size, void* d_ws, size_t ws_size,
                              hipStream_t stream) {
    const float* pred_hm    = (const float*)d_in[0];
    const float* pred_sm    = (const float*)d_in[1];
    const float* ground_res = (const float*)d_in[2];
    const float* mask       = (const float*)d_in[3];
    const int*   centers    = (const int*)d_in[4];
    float* out = (float*)d_out;
    float2* partials = (float2*)d_ws;   // NBLK float2 = 16 KB

    ahl_main_kernel<<<NBLK, 256, 0, stream>>>(pred_hm, pred_sm, mask,
                                              ground_res, centers, out,
                                              partials);
    ahl_reduce_kernel<<<1, 256, 0, stream>>>(partials, out);
}